// Round 10
// baseline (696.594 us; speedup 1.0000x reference)
//
#include <hip/hip_runtime.h>
#include <hip/hip_cooperative_groups.h>
#include <hip/hip_bf16.h>

namespace cg = cooperative_groups;

#define C_DIM 1024
#define H_DIM 512
#define V_DIM 32000
#define B_DIM 16
#define T_DIM 256
#define SPW   8
#define NSLOT 32

typedef unsigned short u16;
typedef unsigned int   u32;
typedef __attribute__((ext_vector_type(8))) short bf16x8;
typedef __attribute__((ext_vector_type(4))) float f32x4;

__device__ __forceinline__ u16 f2b(float f) {
    union { float f; u32 i; } x; x.f = f;
    u32 i = x.i;
    i += 0x7fffu + ((i >> 16) & 1u);   // RNE
    return (u16)(i >> 16);
}
__device__ __forceinline__ float b2f(u16 u) {
    union { u32 i; float f; } x; x.i = ((u32)u) << 16; return x.f;
}
__device__ __forceinline__ float dot8_bf16(uint4 u, const float4 tw0, const float4 tw1) {
    return tw0.x * b2f((u16)(u.x & 0xffff)) + tw0.y * b2f((u16)(u.x >> 16))
         + tw0.z * b2f((u16)(u.y & 0xffff)) + tw0.w * b2f((u16)(u.y >> 16))
         + tw1.x * b2f((u16)(u.z & 0xffff)) + tw1.y * b2f((u16)(u.z >> 16))
         + tw1.z * b2f((u16)(u.w & 0xffff)) + tw1.w * b2f((u16)(u.w >> 16));
}

// dot of tow[v] with Rterm16[cs[s]]; returns value for slot (lane&7) on EVERY lane
__device__ __forceinline__ float sparse8_dot(
    const u16* __restrict__ Rterm16, const float* __restrict__ tow,
    const int* __restrict__ w2s, int v, int lane, int* csOut, int* mycOut)
{
    const float4* twp = (const float4*)(tow + (size_t)v * H_DIM);
    float4 tw0 = twp[lane * 2], tw1 = twp[lane * 2 + 1];
#pragma unroll
    for (int s = 0; s < SPW; s++) csOut[s] = w2s[v * SPW + s];
    uint4 rv[SPW];
#pragma unroll
    for (int s = 0; s < SPW; s++)
        rv[s] = ((const uint4*)(Rterm16 + (size_t)csOut[s] * H_DIM))[lane];
    float d[SPW];
#pragma unroll
    for (int s = 0; s < SPW; s++) {
        d[s] = dot8_bf16(rv[s], tw0, tw1);
        d[s] += __shfl_xor(d[s], 1, 64);
        d[s] += __shfl_xor(d[s], 2, 64);
        d[s] += __shfl_xor(d[s], 4, 64);
    }
    float x = d[0];
    int myc = csOut[0];
#pragma unroll
    for (int s = 1; s < SPW; s++)
        if ((lane & 7) == s) { x = d[s]; myc = csOut[s]; }
    x += __shfl_xor(x, 8, 64);
    x += __shfl_xor(x, 16, 64);
    x += __shfl_xor(x, 32, 64);
    *mycOut = myc;
    return x;
}

// 64x64 bf16 MFMA tile accumulate (K=512)
__device__ __forceinline__ void gemm_tile_acc(
    const u16* __restrict__ A, const u16* __restrict__ Bw,
    int m0, int n0, int tid, u16 As[64][40], u16 Bs[64][40], f32x4 acc[2][2])
{
    const int K = H_DIM;
    int srow = tid >> 2, scol = (tid & 3) << 3;
    int wave = tid >> 6, lane = tid & 63;
    int wr = wave >> 1, wc = wave & 1;
    int quad = lane >> 4, l16 = lane & 15;
    for (int k0 = 0; k0 < K; k0 += 32) {
        uint4 av = *(const uint4*)(A + (size_t)(m0 + srow) * K + k0 + scol);
        uint4 bv = *(const uint4*)(Bw + (size_t)(n0 + srow) * K + k0 + scol);
        __syncthreads();
        *(uint4*)&As[srow][scol] = av;
        *(uint4*)&Bs[srow][scol] = bv;
        __syncthreads();
        bf16x8 af0 = *(const bf16x8*)&As[wr * 32 + l16][quad * 8];
        bf16x8 af1 = *(const bf16x8*)&As[wr * 32 + 16 + l16][quad * 8];
        bf16x8 bf0 = *(const bf16x8*)&Bs[wc * 32 + l16][quad * 8];
        bf16x8 bf1 = *(const bf16x8*)&Bs[wc * 32 + 16 + l16][quad * 8];
        acc[0][0] = __builtin_amdgcn_mfma_f32_16x16x32_bf16(af0, bf0, acc[0][0], 0, 0, 0);
        acc[0][1] = __builtin_amdgcn_mfma_f32_16x16x32_bf16(af0, bf1, acc[0][1], 0, 0, 0);
        acc[1][0] = __builtin_amdgcn_mfma_f32_16x16x32_bf16(af1, bf0, acc[1][0], 0, 0, 0);
        acc[1][1] = __builtin_amdgcn_mfma_f32_16x16x32_bf16(af1, bf1, acc[1][1], 0, 0, 0);
    }
}

// log-semiring 8x8 matrix combine (lane = j*8+i)
__device__ __forceinline__ float lsm_combine(float accv, float mv, int i, int j)
{
    float x[8];
#pragma unroll
    for (int k = 0; k < 8; k++) {
        float a = __shfl(accv, k * 8 + i, 64);
        float b = __shfl(mv,  j * 8 + k, 64);
        x[k] = a + b;
    }
    float mx = fmaxf(fmaxf(fmaxf(x[0], x[1]), fmaxf(x[2], x[3])),
                     fmaxf(fmaxf(x[4], x[5]), fmaxf(x[6], x[7])));
    float s = 0.0f;
#pragma unroll
    for (int k = 0; k < 8; k++) s += expf(x[k] - mx);
    return mx + logf(s);
}

struct MegaArgs {
    const float *start_emb, *start_l1b, *start_l2b, *start_ow, *start_ob;
    const float *state_emb, *trans_l1b, *trans_l2b;
    const float *pret_emb, *term_l1b, *term_l2b, *term_ow, *term_ob;
    const float *srcw[10];   // conversions: 3 emb, 6 mlp weights, proj
    const int *text, *w2s;
    u16 *emb16, *w16, *proj16, *H16, *R16;
    float *TL, *startv, *rowlse, *logZ, *logS, *Mc, *Zpart, *rowZ, *Ssum;
    float *zeroBase;
    int zeroCount;
    float *out;
};

__global__ __launch_bounds__(256, 2) void mega_kern(MegaArgs a)
{
    cg::grid_group grid = cg::this_grid();
    __shared__ __align__(16) u16 As[64][40];
    __shared__ __align__(16) u16 Bs[64][40];
    __shared__ float part[16];

    const size_t CH = (size_t)C_DIM * H_DIM;
    const size_t HH = (size_t)H_DIM * H_DIM;
    int tid = threadIdx.x;
    int bid = blockIdx.x;
    int nb = gridDim.x;
    int gtid = bid * 256 + tid;
    int gsz = nb * 256;
    int wid = tid >> 6, lane = tid & 63;
    int wr = wid >> 1, wc = wid & 1;
    int quad = lane >> 4, l16 = lane & 15;

    // ====== P0: f32->bf16 conversions + zero accumulators =======================
    {
        u16* dst[10] = {a.emb16, a.emb16 + CH, a.emb16 + 2 * CH,
                        a.w16, a.w16 + HH, a.w16 + 2 * HH,
                        a.w16 + 3 * HH, a.w16 + 4 * HH, a.w16 + 5 * HH, a.proj16};
        int n4[10] = {(int)(CH / 4), (int)(CH / 4), (int)(CH / 4),
                      (int)(HH / 4), (int)(HH / 4), (int)(HH / 4),
                      (int)(HH / 4), (int)(HH / 4), (int)(HH / 4), (int)(CH / 4)};
        for (int seg = 0; seg < 10; seg++) {
            const float4* s = (const float4*)a.srcw[seg];
            ushort4* dd = (ushort4*)dst[seg];
            int n = n4[seg];
            for (int idx = gtid; idx < n; idx += gsz) {
                float4 v = s[idx];
                ushort4 o;
                o.x = f2b(v.x); o.y = f2b(v.y); o.z = f2b(v.z); o.w = f2b(v.w);
                dd[idx] = o;
            }
        }
        for (int idx = gtid; idx < a.zeroCount; idx += gsz)
            a.zeroBase[idx] = 0.0f;
    }
    __threadfence();
    grid.sync();

    // ====== P1: MLP layer 1 (384 tiles) =========================================
    for (int tile = bid; tile < 384; tile += nb) {
        int z = tile >> 7, r = tile & 127;
        int m0 = (r & 15) * 64, n0 = (r >> 4) * 64;
        const u16* A = a.emb16 + (size_t)z * CH;
        const u16* W = a.w16 + (size_t)(2 * z) * HH;
        const float* bias = (z == 0) ? a.start_l1b : (z == 1) ? a.trans_l1b : a.term_l1b;
        u16* out = a.H16 + (size_t)z * CH;
        f32x4 acc[2][2] = {};
        gemm_tile_acc(A, W, m0, n0, tid, As, Bs, acc);
#pragma unroll
        for (int sm = 0; sm < 2; sm++)
#pragma unroll
            for (int sn = 0; sn < 2; sn++) {
                int n = n0 + wc * 32 + sn * 16 + l16;
                float bv = bias[n];
#pragma unroll
                for (int reg = 0; reg < 4; reg++) {
                    int m = m0 + wr * 32 + sm * 16 + quad * 4 + reg;
                    out[(size_t)m * H_DIM + n] = f2b(fmaxf(acc[sm][sn][reg] + bv, 0.0f));
                }
            }
    }
    __threadfence();
    grid.sync();

    // ====== P2: MLP layer 2 + residual ==========================================
    for (int tile = bid; tile < 384; tile += nb) {
        int z = tile >> 7, r = tile & 127;
        int m0 = (r & 15) * 64, n0 = (r >> 4) * 64;
        const u16* A = a.H16 + (size_t)z * CH;
        const u16* W = a.w16 + (size_t)(2 * z + 1) * HH;
        const float* bias = (z == 0) ? a.start_l2b : (z == 1) ? a.trans_l2b : a.term_l2b;
        const u16* resid = a.emb16 + (size_t)z * CH;
        u16* out = a.R16 + (size_t)z * CH;
        f32x4 acc[2][2] = {};
        gemm_tile_acc(A, W, m0, n0, tid, As, Bs, acc);
#pragma unroll
        for (int sm = 0; sm < 2; sm++)
#pragma unroll
            for (int sn = 0; sn < 2; sn++) {
                int n = n0 + wc * 32 + sn * 16 + l16;
                float bv = bias[n];
#pragma unroll
                for (int reg = 0; reg < 4; reg++) {
                    int m = m0 + wr * 32 + sm * 16 + quad * 4 + reg;
                    float v = fmaxf(acc[sm][sn][reg] + bv, 0.0f)
                            + b2f(resid[(size_t)m * H_DIM + n]);
                    out[(size_t)m * H_DIM + n] = f2b(v);
                }
            }
    }
    __threadfence();
    grid.sync();

    // ====== P3: TL GEMM + rowZ + startlog  ||  zsum =============================
    {
        int half = nb >> 1;
        if (bid < half) {
            for (int tile = bid; tile < 256; tile += half) {
                int m0 = (tile & 15) * 64, n0 = (tile >> 4) * 64;
                int slot = tile >> 4;
                f32x4 acc[2][2] = {};
                gemm_tile_acc(a.R16 + CH, a.proj16, m0, n0, tid, As, Bs, acc);
#pragma unroll
                for (int sm = 0; sm < 2; sm++)
#pragma unroll
                    for (int reg = 0; reg < 4; reg++) {
                        int m = m0 + wr * 32 + sm * 16 + quad * 4 + reg;
                        float e2 = 0.0f;
#pragma unroll
                        for (int sn = 0; sn < 2; sn++) {
                            int n = n0 + wc * 32 + sn * 16 + l16;
                            float v = acc[sm][sn][reg];
                            a.TL[(size_t)m * C_DIM + n] = v;
                            e2 += expf(v);
                        }
                        e2 += __shfl_xor(e2, 1, 64);
                        e2 += __shfl_xor(e2, 2, 64);
                        e2 += __shfl_xor(e2, 4, 64);
                        e2 += __shfl_xor(e2, 8, 64);
                        if (l16 == 0)
                            atomicAdd(&a.rowZ[(size_t)slot * C_DIM + m], e2);
                    }
            }
            for (int c = bid * 4 + wid; c < C_DIM; c += half * 4) {
                uint4 rv = ((const uint4*)(a.R16 + (size_t)c * H_DIM))[lane];
                const float4* wp = (const float4*)(a.start_ow);
                float4 w0 = wp[lane * 2], w1 = wp[lane * 2 + 1];
                float d = dot8_bf16(rv, w0, w1);
                for (int off = 1; off < 64; off <<= 1) d += __shfl_xor(d, off, 64);
                if (lane == 0) {
                    d += a.start_ob[0];
                    a.startv[c] = d;
                    atomicAdd(&a.Ssum[c & (NSLOT - 1)], expf(d));
                }
            }
        } else {
            const u16* Rterm16 = a.R16 + 2 * CH;
            int nw = (nb - half) * 4;
            float* slot = a.Zpart + (size_t)(bid & (NSLOT - 1)) * C_DIM;
#pragma unroll 1
            for (int v = (bid - half) * 4 + wid; v < V_DIM; v += nw) {
                int cs[SPW], myc;
                float x = sparse8_dot(Rterm16, a.term_ow, a.w2s, v, lane, cs, &myc);
                float ob = a.term_ob[v];
                u32 dupmask = 0;
#pragma unroll
                for (int s = 1; s < SPW; s++) {
                    bool dp = false;
#pragma unroll
                    for (int s2 = 0; s2 < s; s2++) dp = dp || (cs[s2] == cs[s]);
                    if (dp) dupmask |= (1u << s);
                }
                if (lane < 8 && !((dupmask >> lane) & 1u))
                    atomicAdd(slot + myc, expf(x + ob));
            }
        }
    }
    __threadfence();
    grid.sync();

    // ====== P4a: logZ / rowlse / logS ===========================================
    for (int idx = gtid; idx < 2 * C_DIM + 1; idx += gsz) {
        if (idx < C_DIM) {
            float s = 0.0f;
#pragma unroll
            for (int k = 0; k < NSLOT; k++) s += a.Zpart[(size_t)k * C_DIM + idx];
            a.logZ[idx] = logf(s);
        } else if (idx < 2 * C_DIM) {
            int r = idx - C_DIM;
            float s = 0.0f;
#pragma unroll
            for (int k = 0; k < 16; k++) s += a.rowZ[(size_t)k * C_DIM + r];
            a.rowlse[r] = logf(s);
        } else {
            float s = 0.0f;
#pragma unroll
            for (int k = 0; k < NSLOT; k++) s += a.Ssum[k];
            a.logS[0] = logf(s);
        }
    }
    __threadfence();
    grid.sync();

    // ====== P4b: scanA with register-held obs ===================================
    for (int g = bid * 4 + wid; g < 256; g += nb * 4) {
        const u16* Rterm16 = a.R16 + 2 * CH;
        int b = g >> 4, c = g & 15;
        int t0 = c * 16;
        int cnt = min(16, (T_DIM - 1) - t0);
        int i = lane & 7, j = lane >> 3;
        const int* txt = a.text + b * T_DIM;

        float ov[17];
#pragma unroll
        for (int k = 0; k < 17; k++) {
            if (k <= cnt) {
                int v = txt[t0 + k];
                int cs[SPW], myc;
                float x = sparse8_dot(Rterm16, a.term_ow, a.w2s, v, lane, cs, &myc);
                ov[k] = x + a.term_ob[v] - a.logZ[myc];
            } else ov[k] = 0.0f;
        }
        float acc;
        {
            int vt = txt[t0], vt1 = txt[t0 + 1];
            int ci = a.w2s[vt * SPW + i];
            int cj = a.w2s[vt1 * SPW + j];
            float p = a.TL[(size_t)ci * C_DIM + cj] - a.rowlse[ci]
                    + __shfl(ov[1], j, 64);
            if (t0 == 0) p += a.startv[ci] - a.logS[0] + __shfl(ov[0], i, 64);
            acc = p;
        }
#pragma unroll
        for (int k = 1; k < 16; k++) {
            if (k < cnt) {
                int t = t0 + k;
                int vt = txt[t], vt1 = txt[t + 1];
                int ci = a.w2s[vt * SPW + i];
                int cj = a.w2s[vt1 * SPW + j];
                float p = a.TL[(size_t)ci * C_DIM + cj] - a.rowlse[ci]
                        + __shfl(ov[k + 1], j, 64);
                acc = lsm_combine(acc, p, i, j);
            }
        }
        a.Mc[(size_t)g * 64 + lane] = acc;
    }
    __threadfence();
    grid.sync();

    // ====== P5: scanB (block 0) =================================================
    if (bid == 0) {
        int i = lane & 7, j = lane >> 3;
        for (int b = wid; b < B_DIM; b += 4) {
            const float* base = a.Mc + (size_t)b * 16 * 64;
            float acc = base[lane];
            for (int c = 1; c < 16; c++)
                acc = lsm_combine(acc, base[(size_t)c * 64 + lane], i, j);
            float mx = acc;
            for (int o = 1; o < 64; o <<= 1) mx = fmaxf(mx, __shfl_xor(mx, o, 64));
            float e = expf(acc - mx);
            for (int o = 1; o < 64; o <<= 1) e += __shfl_xor(e, o, 64);
            if (lane == 0) part[b] = mx + logf(e);
        }
        __syncthreads();
        if (tid == 0) {
            float s = 0.0f;
#pragma unroll
            for (int k = 0; k < B_DIM; k++) s += part[k];
            a.out[0] = s;
        }
    }
}

// =========================== FALLBACK (Round-8 proven path) ======================
struct CvtArgs {
    const float* src[10];
    u16*         dst[10];
    int          n[10];
    float*       zero;
    int          zn;
};

__global__ __launch_bounds__(256) void fb_cvt(CvtArgs a)
{
    int seg = blockIdx.y;
    if (seg == 10) {
        for (int i = blockIdx.x * 256 + threadIdx.x; i < a.zn; i += gridDim.x * 256)
            a.zero[i] = 0.0f;
        return;
    }
    const float4* s = (const float4*)a.src[seg];
    ushort4* d = (ushort4*)a.dst[seg];
    int n4 = a.n[seg] >> 2;
    for (int i = blockIdx.x * 256 + threadIdx.x; i < n4; i += gridDim.x * 256) {
        float4 v = s[i];
        ushort4 o;
        o.x = f2b(v.x); o.y = f2b(v.y); o.z = f2b(v.z); o.w = f2b(v.w);
        d[i] = o;
    }
}

struct Mlp16Args {
    const u16*   A[3];
    const u16*   W[3];
    const float* bias[3];
    const u16*   resid[3];
    u16*         out[3];
};

__global__ __launch_bounds__(256) void fb_mlp(Mlp16Args args)
{
    const int N = H_DIM;
    int z = blockIdx.z;
    const u16* A = args.A[z];
    const u16* W = args.W[z];
    const float* bias = args.bias[z];
    const u16* resid = args.resid[z];
    u16* out = args.out[z];
    __shared__ __align__(16) u16 As[64][40];
    __shared__ __align__(16) u16 Bs[64][40];
    int tid = threadIdx.x;
    int m0 = blockIdx.x * 64, n0 = blockIdx.y * 64;
    int wave = tid >> 6, lane = tid & 63;
    int wr = wave >> 1, wc = wave & 1;
    int quad = lane >> 4, l16 = lane & 15;
    f32x4 acc[2][2] = {};
    gemm_tile_acc(A, W, m0, n0, tid, As, Bs, acc);
#pragma unroll
    for (int sm = 0; sm < 2; sm++)
#pragma unroll
        for (int sn = 0; sn < 2; sn++) {
            int n = n0 + wc * 32 + sn * 16 + l16;
            float bv = bias[n];
#pragma unroll
            for (int reg = 0; reg < 4; reg++) {
                int m = m0 + wr * 32 + sm * 16 + quad * 4 + reg;
                float v = fmaxf(acc[sm][sn][reg] + bv, 0.0f);
                if (resid) v += b2f(resid[(size_t)m * N + n]);
                out[(size_t)m * N + n] = f2b(v);
            }
        }
}

__global__ __launch_bounds__(256) void fb_gemm(
    const u16* __restrict__ A, const u16* __restrict__ B, float* __restrict__ out)
{
    __shared__ __align__(16) u16 As[64][40];
    __shared__ __align__(16) u16 Bs[64][40];
    int tid = threadIdx.x;
    int m0 = blockIdx.x * 64, n0 = blockIdx.y * 64;
    int wave = tid >> 6, lane = tid & 63;
    int wr = wave >> 1, wc = wave & 1;
    int quad = lane >> 4, l16 = lane & 15;
    f32x4 acc[2][2] = {};
    gemm_tile_acc(A, B, m0, n0, tid, As, Bs, acc);
#pragma unroll
    for (int sm = 0; sm < 2; sm++)
#pragma unroll
        for (int sn = 0; sn < 2; sn++) {
            int n = n0 + wc * 32 + sn * 16 + l16;
#pragma unroll
            for (int reg = 0; reg < 4; reg++) {
                int m = m0 + wr * 32 + sm * 16 + quad * 4 + reg;
                out[(size_t)m * C_DIM + n] = acc[sm][sn][reg];
            }
        }
}

__global__ __launch_bounds__(256) void fb_startlog(
    const u16* __restrict__ Rstart16, const float* __restrict__ sow,
    const float* __restrict__ sob, float* __restrict__ startv,
    float* __restrict__ Ssum)
{
    int wid = threadIdx.x >> 6, lane = threadIdx.x & 63;
    int c = blockIdx.x * 4 + wid;
    uint4 rv = ((const uint4*)(Rstart16 + (size_t)c * H_DIM))[lane];
    const float4* wp = (const float4*)(sow);
    float4 w0 = wp[lane * 2], w1 = wp[lane * 2 + 1];
    float d = dot8_bf16(rv, w0, w1);
    for (int off = 1; off < 64; off <<= 1) d += __shfl_xor(d, off, 64);
    if (lane == 0) {
        d += sob[0];
        startv[c] = d;
        atomicAdd(Ssum + (blockIdx.x & (NSLOT - 1)), expf(d));
    }
}

__global__ __launch_bounds__(256) void fb_rowlse(const float* __restrict__ TL,
                                                 float* __restrict__ rowlse)
{
    int wid = threadIdx.x >> 6, lane = threadIdx.x & 63;
    int row = blockIdx.x * 4 + wid;
    const float4* p = (const float4*)(TL + (size_t)row * C_DIM);
    float s = 0.0f;
#pragma unroll
    for (int k = 0; k < 4; k++) {
        float4 v = p[lane + 64 * k];
        s += expf(v.x) + expf(v.y) + expf(v.z) + expf(v.w);
    }
    for (int off = 1; off < 64; off <<= 1) s += __shfl_xor(s, off, 64);
    if (lane == 0) rowlse[row] = logf(s);
}

__global__ __launch_bounds__(256) void fb_zsum(
    const u16* __restrict__ Rterm16, const float* __restrict__ tow,
    const float* __restrict__ tob, const int* __restrict__ w2s,
    float* __restrict__ Zpart)
{
    int wid = threadIdx.x >> 6, lane = threadIdx.x & 63;
    int v = blockIdx.x * 4 + wid;
    float* slot = Zpart + (size_t)(blockIdx.x & (NSLOT - 1)) * C_DIM;
    int cs[SPW], myc;
    float x = sparse8_dot(Rterm16, tow, w2s, v, lane, cs, &myc);
    float ob = tob[v];
    u32 dupmask = 0;
#pragma unroll
    for (int s = 1; s < SPW; s++) {
        bool dp = false;
#pragma unroll
        for (int s2 = 0; s2 < s; s2++) dp = dp || (cs[s2] == cs[s]);
        if (dp) dupmask |= (1u << s);
    }
    if (lane < 8 && !((dupmask >> lane) & 1u))
        atomicAdd(slot + myc, expf(x + ob));
}

__global__ __launch_bounds__(256) void fb_obs(
    const u16* __restrict__ Rterm16, const float* __restrict__ tow,
    const float* __restrict__ tob, const int* __restrict__ w2s,
    const int* __restrict__ text, const float* __restrict__ Zpart,
    float* __restrict__ obs)
{
    int wid = threadIdx.x >> 6, lane = threadIdx.x & 63;
    int idx = blockIdx.x * 4 + wid;
    int v = text[idx];
    int cs[SPW], myc;
    float x = sparse8_dot(Rterm16, tow, w2s, v, lane, cs, &myc);
    float ob = tob[v];
    int g = lane >> 3;
    float zp = 0.0f;
#pragma unroll
    for (int k = 0; k < 4; k++)
        zp += Zpart[(size_t)(g * 4 + k) * C_DIM + myc];
    zp += __shfl_xor(zp, 8, 64);
    zp += __shfl_xor(zp, 16, 64);
    zp += __shfl_xor(zp, 32, 64);
    if (lane < 8)
        obs[idx * SPW + lane] = x + ob - logf(zp);
}

__global__ __launch_bounds__(256) void fb_scanA(
    const float* __restrict__ TL, const float* __restrict__ rowlse,
    const float* __restrict__ obs, const float* __restrict__ startv,
    const float* __restrict__ Ssum, const int* __restrict__ text,
    const int* __restrict__ w2s, float* __restrict__ Mc)
{
    int wid = threadIdx.x >> 6, lane = threadIdx.x & 63;
    int g = blockIdx.x * 4 + wid;
    int b = g >> 4, c = g & 15;
    int t0 = c * 16;
    int cnt = min(16, (T_DIM - 1) - t0);
    int i = lane & 7, j = lane >> 3;
    const int* txt = text + b * T_DIM;
    const float* obsb = obs + (size_t)b * T_DIM * SPW;
    float logS = 0.0f;
    if (t0 == 0) {
        float ss = 0.0f;
#pragma unroll
        for (int k = 0; k < NSLOT; k++) ss += Ssum[k];
        logS = logf(ss);
    }
    auto potval = [&](int t) -> float {
        int vt = txt[t], vt1 = txt[t + 1];
        int ci = w2s[vt * SPW + i];
        int cj = w2s[vt1 * SPW + j];
        float p = TL[(size_t)ci * C_DIM + cj] - rowlse[ci] + obsb[(t + 1) * SPW + j];
        if (t == 0) p += startv[ci] - logS + obsb[i];
        return p;
    };
    float acc = potval(t0);
    for (int t = t0 + 1; t < t0 + cnt; t++)
        acc = lsm_combine(acc, potval(t), i, j);
    Mc[(size_t)g * 64 + lane] = acc;
}

__global__ __launch_bounds__(1024) void fb_scanB(const float* __restrict__ Mc,
                                                 float* __restrict__ out)
{
    int wave = threadIdx.x >> 6, lane = threadIdx.x & 63;
    int i = lane & 7, j = lane >> 3;
    __shared__ float part[16];
    const float* base = Mc + (size_t)wave * 16 * 64;
    float acc = base[lane];
    for (int c = 1; c < 16; c++)
        acc = lsm_combine(acc, base[(size_t)c * 64 + lane], i, j);
    float mx = acc;
    for (int o = 1; o < 64; o <<= 1) mx = fmaxf(mx, __shfl_xor(mx, o, 64));
    float e = expf(acc - mx);
    for (int o = 1; o < 64; o <<= 1) e += __shfl_xor(e, o, 64);
    if (lane == 0) part[wave] = mx + logf(e);
    __syncthreads();
    if (threadIdx.x == 0) {
        float s = 0.0f;
#pragma unroll
        for (int k = 0; k < B_DIM; k++) s += part[k];
        out[0] = s;
    }
}

extern "C" void kernel_launch(void* const* d_in, const int* in_sizes, int n_in,
                              void* d_out, int out_size, void* d_ws, size_t ws_size,
                              hipStream_t stream)
{
    char* w = (char*)d_ws;
    const u32 MB = 1u << 20;
    const size_t CH = (size_t)C_DIM * H_DIM;
    const size_t HH = (size_t)H_DIM * H_DIM;

    MegaArgs a;
    a.start_emb = (const float*)d_in[0];
    a.start_l1b = (const float*)d_in[2];
    a.start_l2b = (const float*)d_in[4];
    a.start_ow  = (const float*)d_in[5];
    a.start_ob  = (const float*)d_in[6];
    a.state_emb = (const float*)d_in[7];
    a.trans_l1b = (const float*)d_in[9];
    a.trans_l2b = (const float*)d_in[11];
    a.pret_emb  = (const float*)d_in[13];
    a.term_l1b  = (const float*)d_in[15];
    a.term_l2b  = (const float*)d_in[17];
    a.term_ow   = (const float*)d_in[18];
    a.term_ob   = (const float*)d_in[19];
    a.text      = (const int*)d_in[20];
    a.w2s       = (const int*)d_in[21];
    a.srcw[0] = (const float*)d_in[0];   // start_emb
    a.srcw[1] = (const float*)d_in[7];   // state_emb
    a.srcw[2] = (const float*)d_in[13];  // pret_emb
    a.srcw[3] = (const float*)d_in[1];   // start_l1w
    a.srcw[4] = (const float*)d_in[3];   // start_l2w
    a.srcw[5] = (const float*)d_in[8];   // trans_l1w
    a.srcw[6] = (const float*)d_in[10];  // trans_l2w
    a.srcw[7] = (const float*)d_in[14];  // term_l1w
    a.srcw[8] = (const float*)d_in[16];  // term_l2w
    a.srcw[9] = (const float*)d_in[12];  // proj_w

    a.emb16  = (u16*)(w);
    a.w16    = (u16*)(w + 3u * MB);
    a.proj16 = (u16*)(w + 6u * MB);
    a.H16    = (u16*)(w + 7u * MB);
    a.R16    = (u16*)(w + 10u * MB);
    a.TL     = (float*)(w + 13u * MB);
    a.startv = (float*)(w + 17u * MB);
    a.rowlse = (float*)(w + 17u * MB + 4096);
    a.logZ   = (float*)(w + 17u * MB + 8192);
    a.logS   = (float*)(w + 17u * MB + 12288);
    a.Mc     = (float*)(w + 17u * MB + 16384);
    float* obs = (float*)(w + 17u * MB + 16384 + 65536);
    a.Zpart  = (float*)(w + 18u * MB);
    a.rowZ   = (float*)(w + 18u * MB + 131072);
    a.Ssum   = (float*)(w + 18u * MB + 131072 + 65536);
    a.zeroBase  = a.Zpart;
    a.zeroCount = NSLOT * C_DIM + 16 * C_DIM + NSLOT;
    a.out    = (float*)d_out;

    // -------- try cooperative mega-kernel --------
    int maxPerCU = 0;
    hipError_t qe = hipOccupancyMaxActiveBlocksPerMultiprocessor(&maxPerCU,
                                                                 mega_kern, 256, 0);
    bool done = false;
    if (qe == hipSuccess && maxPerCU >= 1) {
        int nblk = maxPerCU * 256;
        if (nblk > 512) nblk = 512;
        if (nblk >= 16) {
            void* kp[] = { &a };
            if (hipLaunchCooperativeKernel(mega_kern, dim3(nblk), dim3(256),
                                           kp, 0, stream) == hipSuccess)
                done = true;
        }
    }
    if (done) return;

    // -------- fallback: proven multi-kernel path --------
    u16* Hs = a.H16;
    u16* Ht = a.H16 + CH;
    u16* Hp = a.H16 + 2 * CH;
    u16* Rstart16 = a.R16;
    u16* Rtrans16 = a.R16 + CH;
    u16* Rterm16  = a.R16 + 2 * CH;
    dim3 blk256(256);

    CvtArgs cv;
    for (int k = 0; k < 10; k++) cv.src[k] = a.srcw[k];
    cv.dst[0] = a.emb16;          cv.n[0] = (int)CH;
    cv.dst[1] = a.emb16 + CH;     cv.n[1] = (int)CH;
    cv.dst[2] = a.emb16 + 2 * CH; cv.n[2] = (int)CH;
    cv.dst[3] = a.w16;            cv.n[3] = (int)HH;
    cv.dst[4] = a.w16 + HH;       cv.n[4] = (int)HH;
    cv.dst[5] = a.w16 + 2 * HH;   cv.n[5] = (int)HH;
    cv.dst[6] = a.w16 + 3 * HH;   cv.n[6] = (int)HH;
    cv.dst[7] = a.w16 + 4 * HH;   cv.n[7] = (int)HH;
    cv.dst[8] = a.w16 + 5 * HH;   cv.n[8] = (int)HH;
    cv.dst[9] = a.proj16;         cv.n[9] = (int)CH;
    cv.zero = a.zeroBase; cv.zn = a.zeroCount;
    fb_cvt<<<dim3(128, 11), blk256, 0, stream>>>(cv);

    Mlp16Args l1 = {{a.emb16, a.emb16 + CH, a.emb16 + 2 * CH},
                    {a.w16, a.w16 + 2 * HH, a.w16 + 4 * HH},
                    {a.start_l1b, a.trans_l1b, a.term_l1b},
                    {nullptr, nullptr, nullptr},
                    {Hs, Ht, Hp}};
    Mlp16Args l2 = {{Hs, Ht, Hp},
                    {a.w16 + HH, a.w16 + 3 * HH, a.w16 + 5 * HH},
                    {a.start_l2b, a.trans_l2b, a.term_l2b},
                    {a.emb16, a.emb16 + CH, a.emb16 + 2 * CH},
                    {Rstart16, Rtrans16, Rterm16}};
    fb_mlp<<<dim3(16, 8, 3), blk256, 0, stream>>>(l1);
    fb_mlp<<<dim3(16, 8, 3), blk256, 0, stream>>>(l2);
    fb_gemm<<<dim3(16, 16), blk256, 0, stream>>>(Rtrans16, a.proj16, a.TL);
    fb_startlog<<<C_DIM / 4, blk256, 0, stream>>>(Rstart16, a.start_ow, a.start_ob,
                                                  a.startv, a.Ssum);
    fb_zsum<<<V_DIM / 4, blk256, 0, stream>>>(Rterm16, a.term_ow, a.term_ob,
                                              a.w2s, a.Zpart);
    fb_rowlse<<<C_DIM / 4, blk256, 0, stream>>>(a.TL, a.rowlse);
    fb_obs<<<B_DIM * T_DIM / 4, blk256, 0, stream>>>(Rterm16, a.term_ow, a.term_ob,
                                                     a.w2s, a.text, a.Zpart, obs);
    fb_scanA<<<B_DIM * 16 / 4, blk256, 0, stream>>>(a.TL, a.rowlse, obs, a.startv,
                                                    a.Ssum, a.text, a.w2s, a.Mc);
    fb_scanB<<<1, 1024, 0, stream>>>(a.Mc, (float*)d_out);
}

// Round 11
// 279.315 us; speedup vs baseline: 2.4939x; 2.4939x over previous
//
#include <hip/hip_runtime.h>
#include <hip/hip_bf16.h>

#define C_DIM 1024
#define H_DIM 512
#define V_DIM 32000
#define B_DIM 16
#define T_DIM 256
#define SPW   8
#define NSLOT 32

typedef unsigned short u16;
typedef unsigned int   u32;
typedef __attribute__((ext_vector_type(8))) short bf16x8;
typedef __attribute__((ext_vector_type(4))) float f32x4;

__device__ __forceinline__ u16 f2b(float f) {
    union { float f; u32 i; } x; x.f = f;
    u32 i = x.i;
    i += 0x7fffu + ((i >> 16) & 1u);   // RNE
    return (u16)(i >> 16);
}
__device__ __forceinline__ float b2f(u16 u) {
    union { u32 i; float f; } x; x.i = ((u32)u) << 16; return x.f;
}
__device__ __forceinline__ float dot8_bf16(uint4 u, const float4 tw0, const float4 tw1) {
    return tw0.x * b2f((u16)(u.x & 0xffff)) + tw0.y * b2f((u16)(u.x >> 16))
         + tw0.z * b2f((u16)(u.y & 0xffff)) + tw0.w * b2f((u16)(u.y >> 16))
         + tw1.x * b2f((u16)(u.z & 0xffff)) + tw1.y * b2f((u16)(u.z >> 16))
         + tw1.z * b2f((u16)(u.w & 0xffff)) + tw1.w * b2f((u16)(u.w >> 16));
}

// dot of tow[v] with Rterm16[cs[s]]; every lane ends with slot (lane&7)'s value
__device__ __forceinline__ float sparse8_dot(
    const u16* __restrict__ Rterm16, const float* __restrict__ tow,
    const int* __restrict__ w2s, int v, int lane, int* csOut, int* mycOut)
{
    const float4* twp = (const float4*)(tow + (size_t)v * H_DIM);
    float4 tw0 = twp[lane * 2], tw1 = twp[lane * 2 + 1];
#pragma unroll
    for (int s = 0; s < SPW; s++) csOut[s] = w2s[v * SPW + s];
    uint4 rv[SPW];
#pragma unroll
    for (int s = 0; s < SPW; s++)
        rv[s] = ((const uint4*)(Rterm16 + (size_t)csOut[s] * H_DIM))[lane];
    float d[SPW];
#pragma unroll
    for (int s = 0; s < SPW; s++) {
        d[s] = dot8_bf16(rv[s], tw0, tw1);
        d[s] += __shfl_xor(d[s], 1, 64);
        d[s] += __shfl_xor(d[s], 2, 64);
        d[s] += __shfl_xor(d[s], 4, 64);
    }
    float x = d[0];
    int myc = csOut[0];
#pragma unroll
    for (int s = 1; s < SPW; s++)
        if ((lane & 7) == s) { x = d[s]; myc = csOut[s]; }
    x += __shfl_xor(x, 8, 64);
    x += __shfl_xor(x, 16, 64);
    x += __shfl_xor(x, 32, 64);
    *mycOut = myc;
    return x;
}

// 64x64 bf16 MFMA tile accumulate (K=512)
__device__ __forceinline__ void gemm_tile_acc(
    const u16* __restrict__ A, const u16* __restrict__ Bw,
    int m0, int n0, int tid, u16 As[64][40], u16 Bs[64][40], f32x4 acc[2][2])
{
    const int K = H_DIM;
    int srow = tid >> 2, scol = (tid & 3) << 3;
    int wave = tid >> 6, lane = tid & 63;
    int wr = wave >> 1, wc = wave & 1;
    int quad = lane >> 4, l16 = lane & 15;
    for (int k0 = 0; k0 < K; k0 += 32) {
        uint4 av = *(const uint4*)(A + (size_t)(m0 + srow) * K + k0 + scol);
        uint4 bv = *(const uint4*)(Bw + (size_t)(n0 + srow) * K + k0 + scol);
        __syncthreads();
        *(uint4*)&As[srow][scol] = av;
        *(uint4*)&Bs[srow][scol] = bv;
        __syncthreads();
        bf16x8 af0 = *(const bf16x8*)&As[wr * 32 + l16][quad * 8];
        bf16x8 af1 = *(const bf16x8*)&As[wr * 32 + 16 + l16][quad * 8];
        bf16x8 bf0 = *(const bf16x8*)&Bs[wc * 32 + l16][quad * 8];
        bf16x8 bf1 = *(const bf16x8*)&Bs[wc * 32 + 16 + l16][quad * 8];
        acc[0][0] = __builtin_amdgcn_mfma_f32_16x16x32_bf16(af0, bf0, acc[0][0], 0, 0, 0);
        acc[0][1] = __builtin_amdgcn_mfma_f32_16x16x32_bf16(af0, bf1, acc[0][1], 0, 0, 0);
        acc[1][0] = __builtin_amdgcn_mfma_f32_16x16x32_bf16(af1, bf0, acc[1][0], 0, 0, 0);
        acc[1][1] = __builtin_amdgcn_mfma_f32_16x16x32_bf16(af1, bf1, acc[1][1], 0, 0, 0);
    }
}

// log-semiring 8x8 matrix combine (lane = j*8+i)
__device__ __forceinline__ float lsm_combine(float accv, float mv, int i, int j)
{
    float x[8];
#pragma unroll
    for (int k = 0; k < 8; k++) {
        float a = __shfl(accv, k * 8 + i, 64);
        float b = __shfl(mv,  j * 8 + k, 64);
        x[k] = a + b;
    }
    float mx = fmaxf(fmaxf(fmaxf(x[0], x[1]), fmaxf(x[2], x[3])),
                     fmaxf(fmaxf(x[4], x[5]), fmaxf(x[6], x[7])));
    float s = 0.0f;
#pragma unroll
    for (int k = 0; k < 8; k++) s += expf(x[k] - mx);
    return mx + logf(s);
}

// ---------------- K1: f32->bf16 convert + zero accumulators ---------------------
struct CvtArgs {
    const float* src[10];
    u16*         dst[10];
    int          n[10];
    float*       zero;
    int          zn;
};

__global__ __launch_bounds__(256) void cvt_kern(CvtArgs a)
{
    int seg = blockIdx.y;
    if (seg == 10) {
        for (int i = blockIdx.x * 256 + threadIdx.x; i < a.zn; i += gridDim.x * 256)
            a.zero[i] = 0.0f;
        return;
    }
    const float4* s = (const float4*)a.src[seg];
    ushort4* d = (ushort4*)a.dst[seg];
    int n4 = a.n[seg] >> 2;
    for (int i = blockIdx.x * 256 + threadIdx.x; i < n4; i += gridDim.x * 256) {
        float4 v = s[i];
        ushort4 o;
        o.x = f2b(v.x); o.y = f2b(v.y); o.z = f2b(v.z); o.w = f2b(v.w);
        d[i] = o;
    }
}

// ---------------- K2/K3: batched MLP layer (3 problems via z) -------------------
struct Mlp16Args {
    const u16*   A[3];
    const u16*   W[3];
    const float* bias[3];
    const u16*   resid[3];
    u16*         out[3];
};

__global__ __launch_bounds__(256) void mlp_kern(Mlp16Args args)
{
    const int N = H_DIM;
    int z = blockIdx.z;
    const u16* A = args.A[z];
    const u16* W = args.W[z];
    const float* bias = args.bias[z];
    const u16* resid = args.resid[z];
    u16* out = args.out[z];
    __shared__ __align__(16) u16 As[64][40];
    __shared__ __align__(16) u16 Bs[64][40];
    int tid = threadIdx.x;
    int m0 = blockIdx.x * 64, n0 = blockIdx.y * 64;
    int wave = tid >> 6, lane = tid & 63;
    int wr = wave >> 1, wc = wave & 1;
    int quad = lane >> 4, l16 = lane & 15;
    f32x4 acc[2][2] = {};
    gemm_tile_acc(A, W, m0, n0, tid, As, Bs, acc);
#pragma unroll
    for (int sm = 0; sm < 2; sm++)
#pragma unroll
        for (int sn = 0; sn < 2; sn++) {
            int n = n0 + wc * 32 + sn * 16 + l16;
            float bv = bias[n];
#pragma unroll
            for (int reg = 0; reg < 4; reg++) {
                int m = m0 + wr * 32 + sm * 16 + quad * 4 + reg;
                float v = fmaxf(acc[sm][sn][reg] + bv, 0.0f);
                if (resid) v += b2f(resid[(size_t)m * N + n]);
                out[(size_t)m * N + n] = f2b(v);
            }
        }
}

// ---------------- K4: TL GEMM + rowZ partial exp-sums + startlog ----------------
__global__ __launch_bounds__(256) void tl_kern(
    const u16* __restrict__ Rtrans16, const u16* __restrict__ proj16,
    const u16* __restrict__ Rstart16, const float* __restrict__ sow,
    const float* __restrict__ sob, float* __restrict__ TL,
    float* __restrict__ rowZ, float* __restrict__ startv, float* __restrict__ Ssum)
{
    __shared__ __align__(16) u16 As[64][40];
    __shared__ __align__(16) u16 Bs[64][40];
    int tid = threadIdx.x;
    int bid = blockIdx.x;
    int m0 = (bid & 15) * 64, n0 = (bid >> 4) * 64;
    int slot = bid >> 4;
    int wave = tid >> 6, lane = tid & 63;
    int wr = wave >> 1, wc = wave & 1;
    int quad = lane >> 4, l16 = lane & 15;
    f32x4 acc[2][2] = {};
    gemm_tile_acc(Rtrans16, proj16, m0, n0, tid, As, Bs, acc);
#pragma unroll
    for (int sm = 0; sm < 2; sm++)
#pragma unroll
        for (int reg = 0; reg < 4; reg++) {
            int m = m0 + wr * 32 + sm * 16 + quad * 4 + reg;
            float e2 = 0.0f;
#pragma unroll
            for (int sn = 0; sn < 2; sn++) {
                int n = n0 + wc * 32 + sn * 16 + l16;
                float v = acc[sm][sn][reg];
                TL[(size_t)m * C_DIM + n] = v;
                e2 += expf(v);
            }
            e2 += __shfl_xor(e2, 1, 64);
            e2 += __shfl_xor(e2, 2, 64);
            e2 += __shfl_xor(e2, 4, 64);
            e2 += __shfl_xor(e2, 8, 64);
            if (l16 == 0) atomicAdd(&rowZ[(size_t)slot * C_DIM + m], e2);
        }
    // startlog: row c = bid*4 + wave
    {
        int c = bid * 4 + wave;
        uint4 rv = ((const uint4*)(Rstart16 + (size_t)c * H_DIM))[lane];
        const float4* wp = (const float4*)(sow);
        float4 w0 = wp[lane * 2], w1 = wp[lane * 2 + 1];
        float d = dot8_bf16(rv, w0, w1);
        for (int off = 1; off < 64; off <<= 1) d += __shfl_xor(d, off, 64);
        if (lane == 0) {
            d += sob[0];
            startv[c] = d;
            atomicAdd(&Ssum[bid & (NSLOT - 1)], expf(d));
        }
    }
}

// ---------------- K5: rowlse + logS + zsum (one launch) -------------------------
__global__ __launch_bounds__(256) void zr_kern(
    const u16* __restrict__ Rterm16, const float* __restrict__ tow,
    const float* __restrict__ tob, const int* __restrict__ w2s,
    const float* __restrict__ rowZ, const float* __restrict__ Ssum,
    float* __restrict__ Zpart, float* __restrict__ rowlse, float* __restrict__ logS)
{
    int bid = blockIdx.x;
    int tid = threadIdx.x;
    if (bid < 4) {                       // rowlse for row r
        int r = bid * 256 + tid;
        float s = 0.0f;
#pragma unroll
        for (int k = 0; k < 16; k++) s += rowZ[(size_t)k * C_DIM + r];
        rowlse[r] = logf(s);
        return;
    }
    if (bid == 4) {                      // logS
        if (tid == 0) {
            float s = 0.0f;
#pragma unroll
            for (int k = 0; k < NSLOT; k++) s += Ssum[k];
            logS[0] = logf(s);
        }
        return;
    }
    // zsum: one wave per word
    int wid = tid >> 6, lane = tid & 63;
    int v = (bid - 5) * 4 + wid;
    float* slot = Zpart + (size_t)(bid & (NSLOT - 1)) * C_DIM;
    int cs[SPW], myc;
    float x = sparse8_dot(Rterm16, tow, w2s, v, lane, cs, &myc);
    float ob = tob[v];
    u32 dupmask = 0;
#pragma unroll
    for (int s = 1; s < SPW; s++) {
        bool dp = false;
#pragma unroll
        for (int s2 = 0; s2 < s; s2++) dp = dp || (cs[s2] == cs[s]);
        if (dp) dupmask |= (1u << s);
    }
    if (lane < 8 && !((dupmask >> lane) & 1u))
        atomicAdd(slot + myc, expf(x + ob));
}

// ---------------- K6: scanA with fused obs; last block does scanB ---------------
__global__ __launch_bounds__(256) void scan_kern(
    const u16* __restrict__ Rterm16, const float* __restrict__ tow,
    const float* __restrict__ tob, const int* __restrict__ w2s,
    const float* __restrict__ Zpart, const float* __restrict__ TL,
    const float* __restrict__ rowlse, const float* __restrict__ startv,
    const float* __restrict__ logS, const int* __restrict__ text,
    float* __restrict__ Mc, u32* __restrict__ cnt, float* __restrict__ out)
{
    int tid = threadIdx.x;
    int wid = tid >> 6, lane = tid & 63;
    int g = blockIdx.x * 4 + wid;        // 0..255
    int b = g >> 4, c = g & 15;
    int t0 = c * 16;
    int cntT = min(16, (T_DIM - 1) - t0);
    int i = lane & 7, j = lane >> 3;
    const int* txt = text + b * T_DIM;

    float ov[17];
#pragma unroll
    for (int k = 0; k < 17; k++) {
        if (k <= cntT) {
            int v = txt[t0 + k];
            int cs[SPW], myc;
            float x = sparse8_dot(Rterm16, tow, w2s, v, lane, cs, &myc);
            // fold logZ: lane group gz sums 4 slots of state myc
            int gz = lane >> 3;
            float zp = 0.0f;
#pragma unroll
            for (int kk = 0; kk < 4; kk++)
                zp += Zpart[(size_t)(gz * 4 + kk) * C_DIM + myc];
            zp += __shfl_xor(zp, 8, 64);
            zp += __shfl_xor(zp, 16, 64);
            zp += __shfl_xor(zp, 32, 64);
            ov[k] = x + tob[v] - logf(zp);
        } else ov[k] = 0.0f;
    }
    float acc;
    {
        int vt = txt[t0], vt1 = txt[t0 + 1];
        int ci = w2s[vt * SPW + i];
        int cj = w2s[vt1 * SPW + j];
        float p = TL[(size_t)ci * C_DIM + cj] - rowlse[ci] + __shfl(ov[1], j, 64);
        if (t0 == 0) p += startv[ci] - logS[0] + __shfl(ov[0], i, 64);
        acc = p;
    }
#pragma unroll
    for (int k = 1; k < 16; k++) {
        if (k < cntT) {
            int t = t0 + k;
            int vt = txt[t], vt1 = txt[t + 1];
            int ci = w2s[vt * SPW + i];
            int cj = w2s[vt1 * SPW + j];
            float p = TL[(size_t)ci * C_DIM + cj] - rowlse[ci]
                    + __shfl(ov[k + 1], j, 64);
            acc = lsm_combine(acc, p, i, j);
        }
    }
    Mc[(size_t)g * 64 + lane] = acc;

    // ---- last-block-does-scanB (fence/flag) ----
    __threadfence();
    __syncthreads();
    __shared__ u32 isLast;
    if (tid == 0) isLast = (atomicAdd(cnt, 1u) == (u32)(gridDim.x - 1));
    __syncthreads();
    if (!isLast) return;
    __threadfence();

    __shared__ float part[16];
    for (int bb = wid; bb < B_DIM; bb += 4) {
        const float* base = Mc + (size_t)bb * 16 * 64;
        float a2 = base[lane];
        for (int cc = 1; cc < 16; cc++)
            a2 = lsm_combine(a2, base[(size_t)cc * 64 + lane], i, j);
        float mx = a2;
        for (int o = 1; o < 64; o <<= 1) mx = fmaxf(mx, __shfl_xor(mx, o, 64));
        float e = expf(a2 - mx);
        for (int o = 1; o < 64; o <<= 1) e += __shfl_xor(e, o, 64);
        if (lane == 0) part[bb] = mx + logf(e);
    }
    __syncthreads();
    if (tid == 0) {
        float s = 0.0f;
#pragma unroll
        for (int k = 0; k < B_DIM; k++) s += part[k];
        out[0] = s;
    }
}

extern "C" void kernel_launch(void* const* d_in, const int* in_sizes, int n_in,
                              void* d_out, int out_size, void* d_ws, size_t ws_size,
                              hipStream_t stream)
{
    char* w = (char*)d_ws;
    const u32 MB = 1u << 20;
    const size_t CH = (size_t)C_DIM * H_DIM;
    const size_t HH = (size_t)H_DIM * H_DIM;

    const float* start_l1b = (const float*)d_in[2];
    const float* start_l2b = (const float*)d_in[4];
    const float* start_ow  = (const float*)d_in[5];
    const float* start_ob  = (const float*)d_in[6];
    const float* trans_l1b = (const float*)d_in[9];
    const float* trans_l2b = (const float*)d_in[11];
    const float* term_l1b  = (const float*)d_in[15];
    const float* term_l2b  = (const float*)d_in[17];
    const float* term_ow   = (const float*)d_in[18];
    const float* term_ob   = (const float*)d_in[19];
    const int*   text      = (const int*)d_in[20];
    const int*   w2s       = (const int*)d_in[21];

    u16* emb16  = (u16*)(w);                 // 3 MB
    u16* w16    = (u16*)(w + 3u * MB);       // 3 MB
    u16* proj16 = (u16*)(w + 6u * MB);       // 1 MB
    u16* H16    = (u16*)(w + 7u * MB);       // 3 MB
    u16* R16    = (u16*)(w + 10u * MB);      // 3 MB
    float* TL   = (float*)(w + 13u * MB);    // 4 MB
    float* startv = (float*)(w + 17u * MB);               // 4 KB
    float* rowlse = (float*)(w + 17u * MB + 4096);        // 4 KB
    float* logS   = (float*)(w + 17u * MB + 8192);        // 4 B
    float* Mc     = (float*)(w + 17u * MB + 16384);       // 64 KB
    float* Zpart  = (float*)(w + 18u * MB);               // 128 KB
    float* rowZ   = (float*)(w + 18u * MB + 131072);      // 64 KB
    float* Ssum   = (float*)(w + 18u * MB + 131072 + 65536);   // 128 B
    u32*   cnt    = (u32*)(w + 18u * MB + 131072 + 65536 + 128);
    int zeroCount = NSLOT * C_DIM + 16 * C_DIM + NSLOT + 1;    // Zpart..cnt contiguous

    u16* Hs = H16, *Ht = H16 + CH, *Hp = H16 + 2 * CH;
    u16* Rstart16 = R16;
    u16* Rtrans16 = R16 + CH;
    u16* Rterm16  = R16 + 2 * CH;

    dim3 blk256(256);

    CvtArgs cv;
    cv.src[0] = (const float*)d_in[0];  cv.dst[0] = emb16;          cv.n[0] = (int)CH;
    cv.src[1] = (const float*)d_in[7];  cv.dst[1] = emb16 + CH;     cv.n[1] = (int)CH;
    cv.src[2] = (const float*)d_in[13]; cv.dst[2] = emb16 + 2 * CH; cv.n[2] = (int)CH;
    cv.src[3] = (const float*)d_in[1];  cv.dst[3] = w16;            cv.n[3] = (int)HH;
    cv.src[4] = (const float*)d_in[3];  cv.dst[4] = w16 + HH;       cv.n[4] = (int)HH;
    cv.src[5] = (const float*)d_in[8];  cv.dst[5] = w16 + 2 * HH;   cv.n[5] = (int)HH;
    cv.src[6] = (const float*)d_in[10]; cv.dst[6] = w16 + 3 * HH;   cv.n[6] = (int)HH;
    cv.src[7] = (const float*)d_in[14]; cv.dst[7] = w16 + 4 * HH;   cv.n[7] = (int)HH;
    cv.src[8] = (const float*)d_in[16]; cv.dst[8] = w16 + 5 * HH;   cv.n[8] = (int)HH;
    cv.src[9] = (const float*)d_in[12]; cv.dst[9] = proj16;         cv.n[9] = (int)CH;
    cv.zero = Zpart; cv.zn = zeroCount;
    cvt_kern<<<dim3(128, 11), blk256, 0, stream>>>(cv);

    Mlp16Args l1 = {{emb16, emb16 + CH, emb16 + 2 * CH},
                    {w16, w16 + 2 * HH, w16 + 4 * HH},
                    {start_l1b, trans_l1b, term_l1b},
                    {nullptr, nullptr, nullptr},
                    {Hs, Ht, Hp}};
    Mlp16Args l2 = {{Hs, Ht, Hp},
                    {w16 + HH, w16 + 3 * HH, w16 + 5 * HH},
                    {start_l2b, trans_l2b, term_l2b},
                    {emb16, emb16 + CH, emb16 + 2 * CH},
                    {Rstart16, Rtrans16, Rterm16}};
    mlp_kern<<<dim3(16, 8, 3), blk256, 0, stream>>>(l1);
    mlp_kern<<<dim3(16, 8, 3), blk256, 0, stream>>>(l2);

    tl_kern<<<256, blk256, 0, stream>>>(Rtrans16, proj16, Rstart16, start_ow, start_ob,
                                        TL, rowZ, startv, Ssum);

    zr_kern<<<5 + V_DIM / 4, blk256, 0, stream>>>(Rterm16, term_ow, term_ob, w2s,
                                                  rowZ, Ssum, Zpart, rowlse, logS);

    scan_kern<<<64, blk256, 0, stream>>>(Rterm16, term_ow, term_ob, w2s, Zpart,
                                         TL, rowlse, startv, logS, text,
                                         Mc, cnt, (float*)d_out);
}